// Round 8
// baseline (3243.105 us; speedup 1.0000x reference)
//
#include <hip/hip_runtime.h>

#define BB 32
#define SS 256
#define EMBD 256
#define HIDD 512
#define NTAG 45
#define TPAD 48
#define NBLK 16            // worker blocks per direction (32 hcols each)
#define GRID_REC 32        // 2 dirs x 16 blocks
#define GSTR 130           // G_ls row stride (floats)
#define SENT 0x01010101u   // H poison: bf16 0x0101 (~2.4e-38) x2 — unreachable by f2bf(h)

typedef __bf16 bf16x8 __attribute__((ext_vector_type(8)));
typedef float  f32x4  __attribute__((ext_vector_type(4)));
typedef short  s16x8  __attribute__((ext_vector_type(8)));
typedef unsigned u32x4 __attribute__((ext_vector_type(4)));

__device__ __forceinline__ unsigned short f2bf(float x) {
  unsigned u = __builtin_bit_cast(unsigned, x);
  u = (u + 0x7fffu + ((u >> 16) & 1u)) >> 16;  // RNE
  return (unsigned short)u;
}
// fast sigmoid/tanh on v_exp_f32 (2^x) + v_rcp_f32 — no libm
__device__ __forceinline__ float fsig(float x) {
  float e = __builtin_amdgcn_exp2f(-1.44269504f * x);
  return __builtin_amdgcn_rcpf(1.f + e);
}
__device__ __forceinline__ float ftanh(float x) {
  float e = __builtin_amdgcn_exp2f(-2.88539008f * x);
  return 2.f * __builtin_amdgcn_rcpf(1.f + e) - 1.f;
}
__device__ __forceinline__ f32x4 MF(s16x8 a, s16x8 b, f32x4 c) {
  return __builtin_amdgcn_mfma_f32_16x16x32_bf16(
      __builtin_bit_cast(bf16x8, a), __builtin_bit_cast(bf16x8, b), c, 0, 0, 0);
}
__device__ __forceinline__ unsigned has_sent(s16x8 v) {
  u32x4 u = __builtin_bit_cast(u32x4, v);
  return (unsigned)((u.x == SENT) | (u.y == SENT) | (u.z == SENT) | (u.w == SENT));
}

// device-coherent (IF$) store, fire-and-forget — R2..R7-proven semantics
__device__ __forceinline__ void st64_sys(unsigned* p, unsigned a, unsigned b) {
  unsigned long long v = ((unsigned long long)b << 32) | (unsigned long long)a;
  asm volatile("global_store_dwordx2 %0, %1, off sc0 sc1" :: "v"(p), "v"(v) : "memory");
}
// paired device-coherent 16B loads (one waitcnt) — per-chunk h poll
#define LDH2()                                                          \
  asm volatile("global_load_dwordx4 %0, %2, off sc0 sc1\n\t"            \
               "global_load_dwordx4 %1, %3, off sc0 sc1\n\t"            \
               "s_waitcnt vmcnt(0)"                                     \
               : "=&v"(a0), "=&v"(a1) : "v"(p0), "v"(p1) : "memory")

// ---------- merged pack kernel ----------
// blocks [0,12288): weights; [12288,20480): embeddings; [20480,20673): linear
#define NB_W 12288
#define NB_E 8192
#define NB_L 193
__global__ void k_pack(const int* __restrict__ x, const float* __restrict__ emb,
                       const float* __restrict__ wih_f, const float* __restrict__ whh_f,
                       const float* __restrict__ bf_,  const float* __restrict__ wih_b,
                       const float* __restrict__ whh_b, const float* __restrict__ bb_,
                       const float* __restrict__ lin_w, const float* __restrict__ lin_b,
                       unsigned short* __restrict__ E,  unsigned short* __restrict__ Wh,
                       unsigned short* __restrict__ Wie, float* __restrict__ Bh,
                       unsigned short* __restrict__ LW, float* __restrict__ LB) {
  const int bxg = blockIdx.x;
  const int tid = threadIdx.x;
  if (bxg < NB_W) {
    // packed row r2 = oblk*64 + gate*16 + hl  <->  orig row gate*512 + oblk*16 + hl
    long idx = (long)bxg * 256 + tid;            // exact: 2*2048*768
    int k = (int)(idx % 768); long rest = idx / 768;
    int r2 = (int)(rest & 2047); int dir = (int)(rest >> 11);
    int blk = r2 >> 6, rl = r2 & 63, gate = rl >> 4, hl = rl & 15;
    int orig = gate * HIDD + blk * 16 + hl;
    const float* wih = dir ? wih_b : wih_f;
    const float* whh = dir ? whh_b : whh_f;
    if (k < HIDD) Wh[((long)(dir * 2048 + r2)) * 512 + k] = f2bf(whh[(long)orig * HIDD + k]);
    else          Wie[((long)(dir * 2048 + r2)) * 256 + (k - 512)] = f2bf(wih[(long)orig * EMBD + (k - 512)]);
    if (k == 0) {
      const float* bias = dir ? bb_ : bf_;
      Bh[dir * 2048 + r2] = bias[orig];
    }
  } else if (bxg < NB_W + NB_E) {
    int idx = (bxg - NB_W) * 256 + tid;          // exact: S*B*EMB
    int e = idx & 255; int bt = idx >> 8; int b = bt & 31; int t = bt >> 5;
    int tok = x[b * SS + t];
    E[idx] = f2bf(emb[(long)tok * EMBD + e]);
  } else {
    int idx = (bxg - NB_W - NB_E) * 256 + tid;
    if (idx < TPAD * 1024) {
      int tag = idx >> 10; int c = idx & 1023;
      LW[idx] = (tag < NTAG) ? f2bf(lin_w[tag * 1024 + c]) : (unsigned short)0;
    } else if (idx < TPAD * 1024 + TPAD) {
      int tag = idx - TPAD * 1024;
      LB[tag] = (tag < NTAG) ? lin_b[tag] : 0.f;
    }
  }
}

// ---------- persistent bidirectional LSTM recurrence ----------
// Chunk-pipelined sentinel protocol: h column-chunk kk (32 cols) is exactly
// producer block kk's output. Each wave loads chunks straight to VGPRs
// (sc0sc1), retries on sentinel, MFMAs immediately — early producers are
// consumed while waiting for the last. Input projection (E @ Wie^T) fused:
// computed into the same accumulators before the h-poll (hidden under wait).
// One barrier per step; G_ls double-buffered.
__launch_bounds__(256, 1)
__global__ void k_rec(const unsigned short* __restrict__ Wh,
                      const unsigned short* __restrict__ Wie,
                      const float* __restrict__ Bh,
                      const unsigned short* __restrict__ E,
                      unsigned short* __restrict__ H) {
  __shared__ float G_ls[2][32 * GSTR];             // 33280 B total

  const int bx = blockIdx.x;
  const int dir = bx & 1;
  const int blk = bx >> 1;               // 0..15, owns hcols blk*32..+31
  const int tid = threadIdx.x;
  const int w = tid >> 6, lane = tid & 63;
  const int lm = lane & 15, quad = lane >> 4;

  // ---- weights into VGPRs: wave w owns gate-rows blk*128 + w*32 + ns*16 + lm ----
  s16x8 wb[2][16], wie[2][8];
  float bh[2];
  {
    const long rbase = (long)(dir * 2048 + blk * 128 + w * 32 + lm);
#pragma unroll
    for (int ns = 0; ns < 2; ++ns) {
      const unsigned short* wsrc = Wh + (rbase + ns * 16) * 512 + quad * 8;
#pragma unroll
      for (int kk = 0; kk < 16; ++kk) wb[ns][kk] = *(const s16x8*)&wsrc[kk * 32];
      const unsigned short* wesrc = Wie + (rbase + ns * 16) * 256 + quad * 8;
#pragma unroll
      for (int kk = 0; kk < 8; ++kk) wie[ns][kk] = *(const s16x8*)&wesrc[kk * 32];
      bh[ns] = Bh[rbase + ns * 16];
    }
  }

  const int m_act = tid >> 3, cg = tid & 7;   // activation: batch, hcol-quad
  float cst[4] = {0.f, 0.f, 0.f, 0.f};

  unsigned short* Hd = H + (long)dir * SS * BB * HIDD;

  for (int t = 0; t < SS; ++t) {
    const int tE = (dir == 0) ? t : (SS - 1 - t);
    f32x4 acc[2][2] = {};

    // ---- E-part: gates += E[tE] @ Wie^T (h-independent, runs under the wait) ----
    {
      const unsigned short* eb = E + ((long)tE * BB) * EMBD + quad * 8;
#pragma unroll
      for (int kk = 0; kk < 8; ++kk) {
        s16x8 e0 = *(const s16x8*)&eb[(long)lm * EMBD + kk * 32];
        s16x8 e1 = *(const s16x8*)&eb[(long)(16 + lm) * EMBD + kk * 32];
        acc[0][0] = MF(e0, wie[0][kk], acc[0][0]);
        acc[0][1] = MF(e0, wie[1][kk], acc[0][1]);
        acc[1][0] = MF(e1, wie[0][kk], acc[1][0]);
        acc[1][1] = MF(e1, wie[1][kk], acc[1][1]);
      }
    }

    if (t > 0) {
      // ---- h-part: per-chunk poll straight to VGPRs, MFMA as chunks land ----
      const int hslot = (dir == 0) ? (t - 1) : (SS - t);
      const unsigned short* hb = Hd + (long)hslot * BB * HIDD + quad * 8;
#pragma unroll 4
      for (int kk = 0; kk < 16; ++kk) {
        const unsigned short* p0 = hb + (long)lm * HIDD + kk * 32;
        const unsigned short* p1 = hb + (long)(16 + lm) * HIDD + kk * 32;
        s16x8 a0, a1;
        for (;;) {
          LDH2();
          if (!(has_sent(a0) | has_sent(a1))) break;
        }
        acc[0][0] = MF(a0, wb[0][kk], acc[0][0]);
        acc[0][1] = MF(a0, wb[1][kk], acc[0][1]);
        acc[1][0] = MF(a1, wb[0][kk], acc[1][0]);
        acc[1][1] = MF(a1, wb[1][kk], acc[1][1]);
      }
    }

    // ---- gates + bias -> LDS (double-buffered by t parity) ----
    float* G = G_ls[t & 1];
#pragma unroll
    for (int mt = 0; mt < 2; ++mt)
#pragma unroll
      for (int ns = 0; ns < 2; ++ns)
#pragma unroll
        for (int r = 0; r < 4; ++r) {
          int mm = mt * 16 + quad * 4 + r;   // C/D: row=(lane>>4)*4+reg, col=lane&15
          G[mm * GSTR + w * 32 + ns * 16 + lm] = acc[mt][ns][r] + bh[ns];
        }
    __syncthreads();   // the ONLY barrier per step
    // ---- activation: thread -> (batch m_act, hcols 4cg..4cg+3); fire-and-forget ----
    {
      float hv[4];
#pragma unroll
      for (int j = 0; j < 4; ++j) {
        int c = cg * 4 + j, sub = c >> 4, hl = c & 15;
        const float* gp = &G[m_act * GSTR + sub * 64 + hl];
        float si = fsig(gp[0]);
        float sf = fsig(gp[16]);
        float tg = ftanh(gp[32]);
        float so = fsig(gp[48]);
        cst[j] = sf * cst[j] + si * tg;
        hv[j] = so * ftanh(cst[j]);
      }
      int tslot = (dir == 0) ? t : (SS - 1 - t);
      unsigned d0 = (unsigned)f2bf(hv[0]) | ((unsigned)f2bf(hv[1]) << 16);
      unsigned d1 = (unsigned)f2bf(hv[2]) | ((unsigned)f2bf(hv[3]) << 16);
      st64_sys((unsigned*)&Hd[(long)tslot * BB * HIDD + (long)m_act * HIDD + blk * 32 + cg * 4],
               d0, d1);
    }
    // cross-iter G_ls safety: next write to this parity buffer occurs only
    // after the next barrier, which orders it after all activation reads.
  }
}

// ---------- emissions: [8192,1024] x [1024,48] bf16 MFMA ----------
__launch_bounds__(256)
__global__ void k_emis(const unsigned short* __restrict__ H,
                       const unsigned short* __restrict__ LW,
                       const float* __restrict__ LB,
                       float* __restrict__ EM) {
  const int row0 = blockIdx.x * 32;
  const int tid = threadIdx.x;
  const int w = tid >> 6, lane = tid & 63;
  const int lm = lane & 15, quad = lane >> 4;
  const unsigned short* Hf = H;
  const unsigned short* Hb = H + (long)SS * BB * HIDD;

  for (int tile = w; tile < 6; tile += 4) {   // M2 x N3 tiles
    int mt = tile / 3, nt = tile % 3;
    int arow = row0 + mt * 16 + lm;
    int nrow = nt * 16 + lm;
    f32x4 acc = {0.f, 0.f, 0.f, 0.f};
#pragma unroll 4
    for (int kk = 0; kk < 32; ++kk) {
      int k0 = kk * 32 + quad * 8;
      s16x8 asv = (k0 < HIDD) ? *(const s16x8*)&Hf[(long)arow * HIDD + k0]
                              : *(const s16x8*)&Hb[(long)arow * HIDD + (k0 - HIDD)];
      s16x8 bsv = *(const s16x8*)&LW[nrow * 1024 + k0];
      acc = __builtin_amdgcn_mfma_f32_16x16x32_bf16(
          __builtin_bit_cast(bf16x8, asv), __builtin_bit_cast(bf16x8, bsv), acc, 0, 0, 0);
    }
    float bias = LB[nrow];
#pragma unroll
    for (int r = 0; r < 4; ++r) {
      int mm = row0 + mt * 16 + quad * 4 + r;
      EM[(long)mm * TPAD + nrow] = acc[r] + bias;
    }
  }
}

// ---------- CRF: one wave per chain, scaled (linear-space) forward ----------
__global__ void k_crf(const int* __restrict__ tags, const float* __restrict__ start_t,
                      const float* __restrict__ end_t, const float* __restrict__ trans,
                      const float* __restrict__ EM, float* __restrict__ chain) {
  __shared__ float T_ls[NTAG * TPAD];
  __shared__ float ET[48 * 48 + 16];
  __shared__ float P_ls[64];
  const int b = blockIdx.x;
  const int lane = threadIdx.x;   // 64 threads, single wave
  const int j = lane;

  for (int i = lane; i < NTAG * NTAG; i += 64)
    T_ls[(i / NTAG) * TPAD + (i % NTAG)] = trans[i];
  for (int i = lane; i < 48 * 48 + 16; i += 64) ET[i] = 0.f;
  __syncthreads();

  float Mj = -1e30f;
  if (j < NTAG) {
    for (int i = 0; i < NTAG; ++i) Mj = fmaxf(Mj, T_ls[i * TPAD + j]);
    for (int i = 0; i < NTAG; ++i) ET[i * 48 + j] = __expf(T_ls[i * TPAD + j] - Mj);
  }
  __syncthreads();

  float et[48];
#pragma unroll
  for (int i = 0; i < 48; ++i) et[i] = ET[i * 48 + j];

  float part = 0.f;
  for (int t = lane; t < SS; t += 64) {
    int tg = tags[b * SS + t];
    part += EM[((long)t * BB + b) * TPAD + tg];
    if (t + 1 < SS) part += T_ls[tg * TPAD + tags[b * SS + t + 1]];
    if (t == 0)      part += start_t[tg];
    if (t == SS - 1) part += end_t[tg];
  }
  for (int off = 32; off; off >>= 1) part += __shfl_down(part, off);
  float score = __shfl(part, 0);

  float alpha = (j < NTAG) ? (start_t[j] + EM[(long)b * TPAD + j]) : -1e30f;
  float e_next = (j < NTAG) ? EM[((long)BB + b) * TPAD + j] : 0.f;
  for (int t = 1; t < SS; ++t) {
    float e_cur = e_next;
    if (t < SS - 1) e_next = (j < NTAG) ? EM[((long)(t + 1) * BB + b) * TPAD + j] : 0.f;
    float am = alpha;
#pragma unroll
    for (int off = 32; off; off >>= 1) am = fmaxf(am, __shfl_xor(am, off));
    float p = __expf(alpha - am);
    P_ls[lane] = p;
    __builtin_amdgcn_wave_barrier();
    float s0 = 0.f, s1 = 0.f, s2 = 0.f, s3 = 0.f;
#pragma unroll
    for (int i0 = 0; i0 < 48; i0 += 4) {
      f32x4 pv = *(const f32x4*)&P_ls[i0];
      s0 += pv.x * et[i0];
      s1 += pv.y * et[i0 + 1];
      s2 += pv.z * et[i0 + 2];
      s3 += pv.w * et[i0 + 3];
    }
    __builtin_amdgcn_wave_barrier();
    float s = (s0 + s1) + (s2 + s3);
    float na = am + Mj + __logf(s) + e_cur;
    alpha = (j < NTAG) ? na : -1e30f;
  }
  float v = (j < NTAG) ? (alpha + end_t[j]) : -1e30f;
  float mx = v;
  for (int off = 32; off; off >>= 1) mx = fmaxf(mx, __shfl_xor(mx, off));
  float s = __expf(v - mx);
  for (int off = 32; off; off >>= 1) s += __shfl_xor(s, off);
  if (lane == 0) chain[b] = score - (mx + __logf(s));
}

__global__ void k_fin(const float* __restrict__ chain, float* __restrict__ out) {
  int lane = threadIdx.x;
  float v = (lane < BB) ? chain[lane] : 0.f;
  for (int off = 32; off; off >>= 1) v += __shfl_xor(v, off);
  if (lane == 0) out[0] = -v / (float)BB;
}

extern "C" void kernel_launch(void* const* d_in, const int* in_sizes, int n_in,
                              void* d_out, int out_size, void* d_ws, size_t ws_size,
                              hipStream_t stream) {
  const int*   x      = (const int*)d_in[0];
  const int*   tags   = (const int*)d_in[1];
  const float* emb    = (const float*)d_in[2];
  const float* wih_f  = (const float*)d_in[3];
  const float* whh_f  = (const float*)d_in[4];
  const float* b_f    = (const float*)d_in[5];
  const float* wih_b  = (const float*)d_in[6];
  const float* whh_b  = (const float*)d_in[7];
  const float* b_b    = (const float*)d_in[8];
  const float* lin_w  = (const float*)d_in[9];
  const float* lin_b  = (const float*)d_in[10];
  const float* start_t= (const float*)d_in[11];
  const float* end_t  = (const float*)d_in[12];
  const float* trans  = (const float*)d_in[13];

  char* ws = (char*)d_ws;
  size_t off = 0;
  auto alloc = [&](size_t bytes) {
    void* p = ws + off; off = (off + bytes + 255) & ~(size_t)255; return p;
  };
  unsigned short* E   = (unsigned short*)alloc((size_t)SS * BB * EMBD * 2);      // 4 MB
  unsigned short* Wh  = (unsigned short*)alloc((size_t)2 * 2048 * 512 * 2);      // 4 MB
  unsigned short* Wie = (unsigned short*)alloc((size_t)2 * 2048 * 256 * 2);      // 2 MB
  float*          Bh  = (float*)         alloc((size_t)2 * 2048 * 4);
  unsigned short* H   = (unsigned short*)alloc((size_t)2 * SS * BB * HIDD * 2);  // 16 MB
  unsigned short* LW  = (unsigned short*)alloc((size_t)TPAD * 1024 * 2);
  float*          LB  = (float*)         alloc((size_t)TPAD * 4);
  float*          EM  = (float*)         alloc((size_t)SS * BB * TPAD * 4);      // 1.5 MB
  float*          chain = (float*)       alloc((size_t)BB * 4);

  // H poison: every dword becomes SENT (0x01010101) — the reader poll target.
  hipMemsetAsync(H, 0x01, (size_t)2 * SS * BB * HIDD * 2, stream);
  k_pack<<<dim3(NB_W + NB_E + NB_L), dim3(256), 0, stream>>>(
      x, emb, wih_f, whh_f, b_f, wih_b, whh_b, b_b, lin_w, lin_b,
      E, Wh, Wie, Bh, LW, LB);

  void* kargs[] = {&Wh, &Wie, &Bh, &E, &H};
  hipLaunchCooperativeKernel((const void*)k_rec, dim3(GRID_REC), dim3(256), kargs, 0, stream);

  k_emis<<<dim3((SS * BB) / 32), dim3(256), 0, stream>>>(H, LW, LB, EM);
  k_crf<<<dim3(BB), dim3(64), 0, stream>>>(tags, start_t, end_t, trans, EM, chain);
  k_fin<<<dim3(1), dim3(64), 0, stream>>>(chain, (float*)d_out);
}